// Round 1
// baseline (268.518 us; speedup 1.0000x reference)
//
#include <hip/hip_runtime.h>
#include <hip/hip_bf16.h>

// WSDAN fused pipeline, R8.
// Inputs (f32): fm [64][768][676], att_w [192][768] (only rows 0..31 used),
//               att_b [192], fc_w [200][24576], fc_b [200]
// d_out (f32): p [64*200] | fm_n [64*32*768] | att_m [64*32*676]
//
// R8 change: k_att + k_pool fused. Each block = (batch b, spatial quarter sp)
// streams fm[b][:, ptile] through LDS ONCE (bf16), computes the att tile
// (MFMA, K=768 split over 8 waves, cross-wave f32 reduce in LDS) and
// immediately pools with the same tile (MFMA, K=32), pooled acc in registers.
// fm: exactly one HBM read (was HBM + full L3 re-read). att_pad eliminated.
// Cross-block pooled reduce: f32 partials in ws if ws_size allows, else
// atomicAdd into a zeroed pooled buffer.

typedef unsigned short u16;
typedef __bf16 bf16x8_t __attribute__((ext_vector_type(8)));
typedef float f32x4_t __attribute__((ext_vector_type(4)));
typedef unsigned int uint32x4 __attribute__((ext_vector_type(4)));

union Frag { uint32x4 u4; unsigned u[4]; u16 s[8]; bf16x8_t v; };
union BFU { __hip_bfloat16 h; u16 u; };

__device__ inline u16 f2b(float x) { BFU t; t.h = __float2bfloat16(x); return t.u; }

__device__ inline void load8_cvt(const float* p, Frag& f) {
    f32x4_t x0 = *(const f32x4_t*)(p);
    f32x4_t x1 = *(const f32x4_t*)(p + 4);
#pragma unroll
    for (int j = 0; j < 4; ++j) { f.s[j] = f2b(x0[j]); f.s[4 + j] = f2b(x1[j]); }
}

#define MFMA(a, b, c) __builtin_amdgcn_mfma_f32_16x16x32_bf16((a), (b), (c), 0, 0, 0)

// LDS layout for k_fused (dynamic, 155.5 KB):
//   T  : 2 x [768][TPITCH] u16   fm tile, double-buffered (pitch 40 u16 = 80 B,
//                                rows 16B-aligned for b128 ops)
//   red: [8][32][33] f32         per-wave att partials
//   Sb : [32][TPITCH] u16        relu'd att tile (pool A operand)
#define TPITCH 40
#define T_BYTES (768 * TPITCH * 2)              // 61440 per buffer
#define RED_OFF (2 * T_BYTES)                   // 122880
#define RED_BYTES (8 * 32 * 33 * 4)             // 33792
#define SB_OFF (RED_OFF + RED_BYTES)            // 156672
#define LDS_BYTES (SB_OFF + 32 * TPITCH * 2)    // 159232 <= 163840

// ---- Pass 1 (fused): att tile + pooled partial ----
// grid (4, 64), 512 threads (8 waves), 1 block/CU.
// Tiles of 32 spatial cols; 22 tiles split {6,6,5,5} across sp.
// Per tile: [prefetch t+1 to regs] -> att MFMAs (wave wv owns K-slice
// wv*96..+96, A=att_w preloaded in regs) -> barrier -> cross-wave reduce
// (+bias, relu, write att_out f32 + Sb bf16) -> barrier -> pool MFMAs
// (wave wv owns c-slice wv*96..+96, acc in regs) -> commit t+1 -> barrier.
template<bool PART>
__global__ __launch_bounds__(512, 2) void k_fused(
    const float* __restrict__ fm, const float* __restrict__ att_w,
    const float* __restrict__ att_b, float* __restrict__ att_out,
    float* __restrict__ pdst)
{
    const int sp = blockIdx.x;               // spatial quarter 0..3
    const int b  = blockIdx.y;
    const int t  = threadIdx.x;
    const int wv = t >> 6, l = t & 63, q = l >> 4, ln = l & 15;

    const int t0 = (sp < 2) ? sp * 6 : 12 + (sp - 2) * 5;
    const int nt = (sp < 2) ? 6 : 5;

    extern __shared__ char lds[];
    u16*   T   = (u16*)lds;
    float* red = (float*)(lds + RED_OFF);
    u16*   Sb  = (u16*)(lds + SB_OFF);

    // preload att_w A-fragments for this wave's K-slice (read once, not per tile)
    const int kwv = wv * 96;
    Frag AW[2][3];
#pragma unroll
    for (int mh = 0; mh < 2; ++mh)
#pragma unroll
        for (int ks = 0; ks < 3; ++ks)
            load8_cvt(att_w + (size_t)(mh * 16 + ln) * 768 + kwv + ks * 32 + q * 8,
                      AW[mh][ks]);

    const float bias = att_b[t >> 4];        // m owned in the reduce phase

    f32x4_t accp[2][6];                      // pooled acc: [mh][ct], c = kwv+ct*16+ln
#pragma unroll
    for (int i = 0; i < 2; ++i)
#pragma unroll
        for (int j = 0; j < 6; ++j) accp[i][j] = f32x4_t{0.f, 0.f, 0.f, 0.f};

    // staging: thread covers rows rr+128i (i<6), cols q4*8..+7 of the 32-col tile
    const int rr = t >> 2, q4 = t & 3;
    const float* fb = fm + ((size_t)b * 768 + rr) * 676;
    f32x4_t pre[6][2];

    auto loadf = [&](int tile) {
        const int c0 = tile * 32 + q4 * 8;
        const bool ok0 = (c0 + 3) < 676;     // edge tile 21: only cols 672..675
        const bool ok1 = (c0 + 7) < 676;
#pragma unroll
        for (int i = 0; i < 6; ++i) {
            const float* src = fb + (size_t)(i * 128) * 676 + c0;
            pre[i][0] = ok0 ? *(const f32x4_t*)(src)     : f32x4_t{0.f,0.f,0.f,0.f};
            pre[i][1] = ok1 ? *(const f32x4_t*)(src + 4) : f32x4_t{0.f,0.f,0.f,0.f};
        }
    };
    auto commit = [&](int buf) {             // waits the prefetched loads (vmcnt)
        u16* tp = T + buf * (768 * TPITCH);
#pragma unroll
        for (int i = 0; i < 6; ++i) {
            Frag w;
#pragma unroll
            for (int j = 0; j < 4; ++j) {
                w.s[j]     = f2b(pre[i][0][j]);
                w.s[4 + j] = f2b(pre[i][1][j]);
            }
            *(uint32x4*)(tp + (rr + i * 128) * TPITCH + q4 * 8) = w.u4;
        }
    };

    loadf(t0); commit(0); __syncthreads();

    for (int it = 0; it < nt; ++it) {
        const int tile = t0 + it;
        const int buf  = it & 1;
        const u16* tp  = T + buf * (768 * TPITCH);

        if (it + 1 < nt) loadf(tile + 1);    // issue early; awaited in commit

        // --- att partial S_wv[32][32] over K-slice kwv..kwv+96 ---
        f32x4_t sa[2][2];
#pragma unroll
        for (int i = 0; i < 2; ++i)
#pragma unroll
            for (int j = 0; j < 2; ++j) sa[i][j] = f32x4_t{0.f,0.f,0.f,0.f};
#pragma unroll
        for (int ks = 0; ks < 3; ++ks) {
            Frag bfr[2];
#pragma unroll
            for (int n2 = 0; n2 < 2; ++n2) {
                const u16* bp = tp + (kwv + ks * 32 + q * 8) * TPITCH + n2 * 16 + ln;
#pragma unroll
                for (int j = 0; j < 8; ++j) bfr[n2].s[j] = bp[j * TPITCH];
            }
#pragma unroll
            for (int mh = 0; mh < 2; ++mh)
#pragma unroll
                for (int n2 = 0; n2 < 2; ++n2)
                    sa[mh][n2] = MFMA(AW[mh][ks].v, bfr[n2].v, sa[mh][n2]);
        }
        {
            float* rp = red + wv * (32 * 33);
#pragma unroll
            for (int mh = 0; mh < 2; ++mh)
#pragma unroll
                for (int n2 = 0; n2 < 2; ++n2)
#pragma unroll
                    for (int r = 0; r < 4; ++r)
                        rp[(mh * 16 + q * 4 + r) * 33 + n2 * 16 + ln] = sa[mh][n2][r];
        }
        __syncthreads();                     // (A) partials visible

        // --- reduce 8 partials + bias, relu; write att_out + Sb ---
        {
            const int m  = t >> 4;
            const int pp = (t & 15) * 2;
            float v0 = bias, v1 = bias;
#pragma unroll
            for (int w8 = 0; w8 < 8; ++w8) {
                const float* rp = red + w8 * (32 * 33) + m * 33 + pp;
                v0 += rp[0]; v1 += rp[1];
            }
            v0 = fmaxf(v0, 0.f); v1 = fmaxf(v1, 0.f);
            const int p = tile * 32 + pp;
            float* ao = att_out + (size_t)(b * 32 + m) * 676 + p;
            if (p + 1 < 676) { ao[0] = v0; ao[1] = v1; }
            // zero-padded T cols guarantee pad att values never reach pooled
            *(unsigned*)(Sb + m * TPITCH + pp) =
                (unsigned)f2b(v0) | ((unsigned)f2b(v1) << 16);
        }
        __syncthreads();                     // (B) Sb visible

        // --- pool: accp[m][c] += sum_p S[m][p] * T[c][p], wave's 96-c slice ---
        {
            Frag af[2];
#pragma unroll
            for (int mh = 0; mh < 2; ++mh)
                af[mh].u4 = *(const uint32x4*)(Sb + (mh * 16 + ln) * TPITCH + q * 8);
#pragma unroll
            for (int ct = 0; ct < 6; ++ct) {
                Frag bfr;
                bfr.u4 = *(const uint32x4*)(tp + (kwv + ct * 16 + ln) * TPITCH + q * 8);
#pragma unroll
                for (int mh = 0; mh < 2; ++mh)
                    accp[mh][ct] = MFMA(af[mh].v, bfr.v, accp[mh][ct]);
            }
        }

        if (it + 1 < nt) commit(buf ^ 1);    // vmcnt wait = the HBM-bound phase
        __syncthreads();                     // (C) next T ready, red reusable
    }

    // epilogue: pooled partial, pre-scaled by 1/676
    const float sc = 1.0f / 676.0f;
#pragma unroll
    for (int mh = 0; mh < 2; ++mh)
#pragma unroll
        for (int ct = 0; ct < 6; ++ct) {
            const int c = kwv + ct * 16 + ln;
#pragma unroll
            for (int r = 0; r < 4; ++r) {
                const int m = mh * 16 + q * 4 + r;
                const float v = accp[mh][ct][r] * sc;
                if constexpr (PART)
                    pdst[((size_t)(sp * 64 + b) * 32 + m) * 768 + c] = v;
                else
                    atomicAdd(pdst + ((size_t)(b * 32 + m)) * 768 + c, v);
            }
        }
}

// ---- Pass 2: reduce split partials (if PART) + p_sums[b] = sum|pooled[b]| ----
template<bool PART>
__global__ __launch_bounds__(256) void k_psum(
    const float* __restrict__ src, float* __restrict__ pooled,
    float* __restrict__ p_sums)
{
    const int b = blockIdx.x, t = threadIdx.x;
    const size_t base = (size_t)b * 24576;
    float s = 0.f;
#pragma unroll
    for (int i = 0; i < 24; ++i) {
        const size_t idx = base + (size_t)(i * 1024 + t * 4);
        if constexpr (PART) {
            f32x4_t v0 = *(const f32x4_t*)(src + idx);
            f32x4_t v1 = *(const f32x4_t*)(src + 1572864 + idx);
            f32x4_t v2 = *(const f32x4_t*)(src + 3145728 + idx);
            f32x4_t v3 = *(const f32x4_t*)(src + 4718592 + idx);
            f32x4_t o;
#pragma unroll
            for (int j = 0; j < 4; ++j) {
                o[j] = (v0[j] + v1[j]) + (v2[j] + v3[j]);
                s += fabsf(o[j]);
            }
            *(f32x4_t*)(pooled + idx) = o;
        } else {
            f32x4_t o = *(const f32x4_t*)(src + idx);
#pragma unroll
            for (int j = 0; j < 4; ++j) s += fabsf(o[j]);
        }
    }
    __shared__ float rs[4];
    for (int off = 32; off > 0; off >>= 1) s += __shfl_down(s, off);
    if ((t & 63) == 0) rs[t >> 6] = s;
    __syncthreads();
    if (t == 0) p_sums[b] = rs[0] + rs[1] + rs[2] + rs[3];
}

// ---- Pass 3: signed sqrt + L2 normalize (unchanged) ----
__global__ __launch_bounds__(256) void k_norm(
    const float* __restrict__ pooled, const float* __restrict__ p_sums,
    float* __restrict__ fm_out, u16* __restrict__ fmn16)
{
    const int b = blockIdx.x;
    const size_t base = (size_t)b * 24576 + (size_t)blockIdx.y * 2048;
    const float tot = p_sums[b] + 24576.f * 1e-12f;
    const float inv = 1.f / fmaxf(sqrtf(tot), 1e-12f);
    const int t = threadIdx.x;
#pragma unroll
    for (int i = 0; i < 8; ++i) {
        const size_t idx = base + i * 256 + t;
        float x = pooled[idx];
        float v = (x == 0.f) ? 0.f : copysignf(sqrtf(fabsf(x) + 1e-12f), x);
        float o = v * inv;
        fm_out[idx] = o;
        fmn16[idx]  = f2b(o);
    }
}

// ---- Pass 4: p partials, K=24576 split into 48 slabs of 512 (unchanged) ----
__global__ __launch_bounds__(256) void k_fc(
    const u16* __restrict__ fmn16, const float* __restrict__ fc_w,
    float* __restrict__ p_part)
{
    const int ntile = blockIdx.x;          // 0..12
    const int slab  = blockIdx.y;          // 0..47
    const int t = threadIdx.x;
    const int wv = t >> 6, l = t & 63, q = l >> 4, ln = l & 15;
    const int n = ntile * 16 + ln;
    const int kbase = slab * 512;

    const u16*   Ab = fmn16 + (size_t)(wv * 16 + ln) * 24576 + kbase + q * 8;
    const float* Bb = fc_w + (size_t)n * 24576 + kbase + q * 8;
    const bool nok = n < 200;

    f32x4_t acc = {0.f, 0.f, 0.f, 0.f};
#pragma unroll
    for (int kk = 0; kk < 512; kk += 32) {
        Frag af, bf2;
        af.u4 = *(const uint32x4*)(Ab + kk);
        if (nok) load8_cvt(Bb + kk, bf2);
        else { bf2.u[0] = 0u; bf2.u[1] = 0u; bf2.u[2] = 0u; bf2.u[3] = 0u; }
        acc = MFMA(af.v, bf2.v, acc);
    }
#pragma unroll
    for (int r = 0; r < 4; ++r) {
        const int bb = wv * 16 + q * 4 + r;
        p_part[(size_t)(slab * 64 + bb) * 208 + ntile * 16 + ln] = acc[r];
    }
}

// ---- Pass 5: reduce 48 slabs, scale 100, + bias (unchanged) ----
__global__ __launch_bounds__(256) void k_fin(
    const float* __restrict__ p_part, const float* __restrict__ fc_b,
    float* __restrict__ p_out)
{
    const int tid = blockIdx.x * 256 + threadIdx.x;   // 50*256 == 12800
    const int b = tid / 200, n = tid - b * 200;
    float s = 0.f;
#pragma unroll
    for (int sl = 0; sl < 48; ++sl) s += p_part[(size_t)(sl * 64 + b) * 208 + n];
    p_out[tid] = s * 100.f + fc_b[n];
}

extern "C" void kernel_launch(void* const* d_in, const int* in_sizes, int n_in,
                              void* d_out, int out_size, void* d_ws, size_t ws_size,
                              hipStream_t stream)
{
    const float* fm    = (const float*)d_in[0];
    const float* att_w = (const float*)d_in[1];
    const float* att_b = (const float*)d_in[2];
    const float* fc_w  = (const float*)d_in[3];
    const float* fc_b  = (const float*)d_in[4];

    float* out     = (float*)d_out;
    float* p_out   = out;                         // [64][200]
    float* fm_out  = out + 12800;                 // [64][32][768]
    float* att_out = out + 12800 + 64 * 32 * 768; // [64][32][676]

    char* ws = (char*)d_ws;
    const size_t PART_B = 25165824;   // [4][64][32][768] f32
    const size_t POOL_B = 6291456;    // [64][32][768] f32
    const size_t FMN_B  = 3145728;    // [64][24576] bf16
    const bool use_part = ws_size >= PART_B + POOL_B + FMN_B + 256;

    float* pooled; float* p_part; float* p_sums; u16* fmn16; float* part = nullptr;
    if (use_part) {
        part   = (float*)ws;
        pooled = (float*)(ws + PART_B);
        fmn16  = (u16*)(ws + PART_B + POOL_B);
        p_sums = (float*)(ws + PART_B + POOL_B + FMN_B);
        p_part = (float*)ws;                      // overlays part (dead by k_fc)
    } else {
        pooled = (float*)ws;
        fmn16  = (u16*)(ws + POOL_B);
        p_sums = (float*)(ws + POOL_B + FMN_B);
        p_part = (float*)ws;                      // overlays pooled (dead by k_fc)
        hipMemsetAsync(pooled, 0, POOL_B, stream);
    }

    static int attr_done = 0;
    if (!attr_done) {
        hipFuncSetAttribute(reinterpret_cast<const void*>(&k_fused<true>),
            hipFuncAttributeMaxDynamicSharedMemorySize, LDS_BYTES);
        hipFuncSetAttribute(reinterpret_cast<const void*>(&k_fused<false>),
            hipFuncAttributeMaxDynamicSharedMemorySize, LDS_BYTES);
        attr_done = 1;
    }

    if (use_part) {
        k_fused<true><<<dim3(4, 64), 512, LDS_BYTES, stream>>>(
            fm, att_w, att_b, att_out, part);
        k_psum<true><<<64, 256, 0, stream>>>(part, pooled, p_sums);
    } else {
        k_fused<false><<<dim3(4, 64), 512, LDS_BYTES, stream>>>(
            fm, att_w, att_b, att_out, pooled);
        k_psum<false><<<64, 256, 0, stream>>>(pooled, pooled, p_sums);
    }
    k_norm<<<dim3(64, 12), 256, 0, stream>>>(pooled, p_sums, fm_out, fmn16);
    k_fc  <<<dim3(13, 48), 256, 0, stream>>>(fmn16, fc_w, p_part);
    k_fin <<<dim3(50),     256, 0, stream>>>(p_part, fc_b, p_out);
}

// Round 3
// 255.634 us; speedup vs baseline: 1.0504x; 1.0504x over previous
//
#include <hip/hip_runtime.h>
#include <hip/hip_bf16.h>

// WSDAN fused pipeline, R10.
// Inputs (f32): fm [64][768][676], att_w [192][768] (rows 0..31 used),
//               att_b [192], fc_w [200][24576], fc_b [200]
// d_out (f32): p [64*200] | fm_n [64*32*768] | att_m [64*32*676]
//
// R10 = R8 (known-correct) + two safe changes:
//  (1) XOR-chunk swizzle on the fm LDS tile: element (c,p) stored at column
//      ((p>>3) ^ ((c>>3)&3))*8 + (p&7). Staging writes and pool reads stay
//      16B-contiguous; att B-frag ds_read_u16 goes 4-way -> 2-way bank
//      conflict (q enters the bank formula via the XOR). Pure bijective
//      storage permutation applied at all 3 access sites.
//  (2) k_psum grid 64 -> (64,4) (was 25% of CUs); per-chunk |sums| in
//      p_sums[64][4], summed by k_norm. No atomics.

typedef unsigned short u16;
typedef __bf16 bf16x8_t __attribute__((ext_vector_type(8)));
typedef float f32x4_t __attribute__((ext_vector_type(4)));
typedef unsigned int uint32x4 __attribute__((ext_vector_type(4)));

union Frag { uint32x4 u4; unsigned u[4]; u16 s[8]; bf16x8_t v; };
union BFU { __hip_bfloat16 h; u16 u; };

__device__ inline u16 f2b(float x) { BFU t; t.h = __float2bfloat16(x); return t.u; }

__device__ inline void load8_cvt(const float* p, Frag& f) {
    f32x4_t x0 = *(const f32x4_t*)(p);
    f32x4_t x1 = *(const f32x4_t*)(p + 4);
#pragma unroll
    for (int j = 0; j < 4; ++j) { f.s[j] = f2b(x0[j]); f.s[4 + j] = f2b(x1[j]); }
}

#define MFMA(a, b, c) __builtin_amdgcn_mfma_f32_16x16x32_bf16((a), (b), (c), 0, 0, 0)

// LDS layout for k_fused (dynamic, 155.5 KB):
//   T  : 2 x [768][40] u16   fm tile, double-buffered, XOR-chunk swizzled:
//        off_u16(c,p) = c*40 + ((p>>3) ^ ((c>>3)&3))*8 + (p&7)
//   red: [8][32][33] f32     per-wave att partials
//   Sb : [32][40] u16        relu'd att tile (pool A operand)
#define TPITCH 40
#define T_BYTES (768 * TPITCH * 2)              // 61440 per buffer
#define RED_OFF (2 * T_BYTES)                   // 122880
#define RED_BYTES (8 * 32 * 33 * 4)             // 33792
#define SB_OFF (RED_OFF + RED_BYTES)            // 156672
#define LDS_BYTES (SB_OFF + 32 * TPITCH * 2)    // 159232 <= 163840

// ---- Pass 1 (fused): att tile + pooled partial ----
// grid (4, 64), 512 threads (8 waves), 1 block/CU.
// Tiles of 32 spatial cols; 22 tiles split {6,6,5,5} across sp.
template<bool PART>
__global__ __launch_bounds__(512, 2) void k_fused(
    const float* __restrict__ fm, const float* __restrict__ att_w,
    const float* __restrict__ att_b, float* __restrict__ att_out,
    float* __restrict__ pdst)
{
    const int sp = blockIdx.x;               // spatial quarter 0..3
    const int b  = blockIdx.y;
    const int t  = threadIdx.x;
    const int wv = t >> 6, l = t & 63, q = l >> 4, ln = l & 15;

    const int t0 = (sp < 2) ? sp * 6 : 12 + (sp - 2) * 5;
    const int nt = (sp < 2) ? 6 : 5;

    extern __shared__ char lds[];
    u16*   T   = (u16*)lds;
    float* red = (float*)(lds + RED_OFF);
    u16*   Sb  = (u16*)(lds + SB_OFF);

    // preload att_w A-fragments for this wave's K-slice (read once, not per tile)
    const int kwv = wv * 96;
    Frag AW[2][3];
#pragma unroll
    for (int mh = 0; mh < 2; ++mh)
#pragma unroll
        for (int ks = 0; ks < 3; ++ks)
            load8_cvt(att_w + (size_t)(mh * 16 + ln) * 768 + kwv + ks * 32 + q * 8,
                      AW[mh][ks]);

    const float bias = att_b[t >> 4];        // m owned in the reduce phase

    f32x4_t accp[2][6];                      // pooled acc: [mh][ct], c = kwv+ct*16+ln
#pragma unroll
    for (int i = 0; i < 2; ++i)
#pragma unroll
        for (int j = 0; j < 6; ++j) accp[i][j] = f32x4_t{0.f, 0.f, 0.f, 0.f};

    // staging: thread covers c-rows rr+128i (i<6), p-cols q4*8..+7 of the tile
    const int rr = t >> 2, q4 = t & 3;
    const float* fb = fm + ((size_t)b * 768 + rr) * 676;
    f32x4_t pre[6][2];
    // swizzled write base; (c>>3)&3 is i-invariant (c = rr + i*128, 128>>3 = 16)
    const int wbase = rr * TPITCH + ((q4 ^ ((rr >> 3) & 3)) << 3);

    auto loadf = [&](int tile) {
        const int c0 = tile * 32 + q4 * 8;
        const bool ok0 = (c0 + 3) < 676;     // edge tile 21: only cols 672..675
        const bool ok1 = (c0 + 7) < 676;
#pragma unroll
        for (int i = 0; i < 6; ++i) {
            const float* src = fb + (size_t)(i * 128) * 676 + c0;
            pre[i][0] = ok0 ? *(const f32x4_t*)(src)     : f32x4_t{0.f,0.f,0.f,0.f};
            pre[i][1] = ok1 ? *(const f32x4_t*)(src + 4) : f32x4_t{0.f,0.f,0.f,0.f};
        }
    };
    auto commit = [&](int buf) {             // waits the prefetched loads (vmcnt)
        u16* tp = T + buf * (768 * TPITCH);
#pragma unroll
        for (int i = 0; i < 6; ++i) {
            Frag w;
#pragma unroll
            for (int j = 0; j < 4; ++j) {
                w.s[j]     = f2b(pre[i][0][j]);
                w.s[4 + j] = f2b(pre[i][1][j]);
            }
            *(uint32x4*)(tp + wbase + i * (128 * TPITCH)) = w.u4;
        }
    };

    loadf(t0); commit(0); __syncthreads();

    for (int it = 0; it < nt; ++it) {
        const int tile = t0 + it;
        const int buf  = it & 1;
        const u16* tp  = T + buf * (768 * TPITCH);

        if (it + 1 < nt) loadf(tile + 1);    // issue early; awaited in commit

        // --- att partial S_wv[32][32] over K-slice kwv..kwv+96 ---
        // B element (c = kwv+ks*32+q*8+j, p = n2*16+ln); (c>>3)&3 == q here,
        // so stored chunk = (n2*2 + (ln>>3)) ^ q  -> 2-way banks across wave.
        f32x4_t sa[2][2];
#pragma unroll
        for (int i = 0; i < 2; ++i)
#pragma unroll
            for (int j = 0; j < 2; ++j) sa[i][j] = f32x4_t{0.f,0.f,0.f,0.f};
#pragma unroll
        for (int ks = 0; ks < 3; ++ks) {
            Frag bfr[2];
#pragma unroll
            for (int n2 = 0; n2 < 2; ++n2) {
                const u16* bp = tp + (kwv + ks * 32 + q * 8) * TPITCH
                              + (((n2 * 2 + (ln >> 3)) ^ q) << 3) + (ln & 7);
#pragma unroll
                for (int j = 0; j < 8; ++j) bfr[n2].s[j] = bp[j * TPITCH];
            }
#pragma unroll
            for (int mh = 0; mh < 2; ++mh)
#pragma unroll
                for (int n2 = 0; n2 < 2; ++n2)
                    sa[mh][n2] = MFMA(AW[mh][ks].v, bfr[n2].v, sa[mh][n2]);
        }
        {
            float* rp = red + wv * (32 * 33);
#pragma unroll
            for (int mh = 0; mh < 2; ++mh)
#pragma unroll
                for (int n2 = 0; n2 < 2; ++n2)
#pragma unroll
                    for (int r = 0; r < 4; ++r)
                        rp[(mh * 16 + q * 4 + r) * 33 + n2 * 16 + ln] = sa[mh][n2][r];
        }
        __syncthreads();                     // (A) partials visible

        // --- reduce 8 partials + bias, relu; write att_out + Sb ---
        {
            const int m  = t >> 4;
            const int pp = (t & 15) * 2;
            float v0 = bias, v1 = bias;
#pragma unroll
            for (int w8 = 0; w8 < 8; ++w8) {
                const float* rp = red + w8 * (32 * 33) + m * 33 + pp;
                v0 += rp[0]; v1 += rp[1];
            }
            v0 = fmaxf(v0, 0.f); v1 = fmaxf(v1, 0.f);
            const int p = tile * 32 + pp;
            float* ao = att_out + (size_t)(b * 32 + m) * 676 + p;
            if (p + 1 < 676) { ao[0] = v0; ao[1] = v1; }
            // T pad cols (invalid p) are zeroed -> pad att never reaches pooled
            *(unsigned*)(Sb + m * TPITCH + pp) =
                (unsigned)f2b(v0) | ((unsigned)f2b(v1) << 16);
        }
        __syncthreads();                     // (B) Sb visible

        // --- pool: accp[m][c] += sum_p S[m][p] * T[c][p] (wave's 96-c slice)
        // B element (c = kwv+ct*16+ln, p = q*8+j): stored chunk =
        // q ^ ((2*ct + (ln>>3)) & 3); 8 u16 contiguous -> b128.
        {
            Frag af[2];
#pragma unroll
            for (int mh = 0; mh < 2; ++mh)
                af[mh].u4 = *(const uint32x4*)(Sb + (mh * 16 + ln) * TPITCH + q * 8);
#pragma unroll
            for (int ct = 0; ct < 6; ++ct) {
                Frag bfr;
                bfr.u4 = *(const uint32x4*)(tp + (kwv + ct * 16 + ln) * TPITCH
                           + ((q ^ ((2 * ct + (ln >> 3)) & 3)) << 3));
#pragma unroll
                for (int mh = 0; mh < 2; ++mh)
                    accp[mh][ct] = MFMA(af[mh].v, bfr.v, accp[mh][ct]);
            }
        }

        if (it + 1 < nt) commit(buf ^ 1);    // vmcnt wait = the HBM-bound phase
        __syncthreads();                     // (C) next T ready, red reusable
    }

    // epilogue: pooled partial, pre-scaled by 1/676
    const float sc = 1.0f / 676.0f;
#pragma unroll
    for (int mh = 0; mh < 2; ++mh)
#pragma unroll
        for (int ct = 0; ct < 6; ++ct) {
            const int c = kwv + ct * 16 + ln;
#pragma unroll
            for (int r = 0; r < 4; ++r) {
                const int m = mh * 16 + q * 4 + r;
                const float v = accp[mh][ct][r] * sc;
                if constexpr (PART)
                    pdst[((size_t)(sp * 64 + b) * 32 + m) * 768 + c] = v;
                else
                    atomicAdd(pdst + ((size_t)(b * 32 + m)) * 768 + c, v);
            }
        }
}

// ---- Pass 2: reduce split partials + per-chunk |sum| -> p_sums[64][4] ----
// grid (64, 4): full-device BW.
template<bool PART>
__global__ __launch_bounds__(256) void k_psum(
    const float* __restrict__ src, float* __restrict__ pooled,
    float* __restrict__ p_sums)
{
    const int b = blockIdx.x, ch = blockIdx.y, t = threadIdx.x;
    const size_t base = (size_t)b * 24576 + (size_t)ch * 6144;
    float s = 0.f;
#pragma unroll
    for (int i = 0; i < 6; ++i) {
        const size_t idx = base + (size_t)(i * 1024 + t * 4);
        if constexpr (PART) {
            f32x4_t v0 = *(const f32x4_t*)(src + idx);
            f32x4_t v1 = *(const f32x4_t*)(src + 1572864 + idx);
            f32x4_t v2 = *(const f32x4_t*)(src + 3145728 + idx);
            f32x4_t v3 = *(const f32x4_t*)(src + 4718592 + idx);
            f32x4_t o;
#pragma unroll
            for (int j = 0; j < 4; ++j) {
                o[j] = (v0[j] + v1[j]) + (v2[j] + v3[j]);
                s += fabsf(o[j]);
            }
            *(f32x4_t*)(pooled + idx) = o;
        } else {
            f32x4_t o = *(const f32x4_t*)(src + idx);
#pragma unroll
            for (int j = 0; j < 4; ++j) s += fabsf(o[j]);
        }
    }
    __shared__ float rs[4];
    for (int off = 32; off > 0; off >>= 1) s += __shfl_down(s, off);
    if ((t & 63) == 0) rs[t >> 6] = s;
    __syncthreads();
    if (t == 0) p_sums[b * 4 + ch] = rs[0] + rs[1] + rs[2] + rs[3];
}

// ---- Pass 3: signed sqrt + L2 normalize ----
__global__ __launch_bounds__(256) void k_norm(
    const float* __restrict__ pooled, const float* __restrict__ p_sums,
    float* __restrict__ fm_out, u16* __restrict__ fmn16)
{
    const int b = blockIdx.x;
    const size_t base = (size_t)b * 24576 + (size_t)blockIdx.y * 2048;
    const float* s4 = p_sums + b * 4;
    const float tot = ((s4[0] + s4[1]) + (s4[2] + s4[3])) + 24576.f * 1e-12f;
    const float inv = 1.f / fmaxf(sqrtf(tot), 1e-12f);
    const int t = threadIdx.x;
#pragma unroll
    for (int i = 0; i < 8; ++i) {
        const size_t idx = base + i * 256 + t;
        float x = pooled[idx];
        float v = (x == 0.f) ? 0.f : copysignf(sqrtf(fabsf(x) + 1e-12f), x);
        float o = v * inv;
        fm_out[idx] = o;
        fmn16[idx]  = f2b(o);
    }
}

// ---- Pass 4: p partials, K=24576 split into 48 slabs of 512 ----
__global__ __launch_bounds__(256) void k_fc(
    const u16* __restrict__ fmn16, const float* __restrict__ fc_w,
    float* __restrict__ p_part)
{
    const int ntile = blockIdx.x;          // 0..12
    const int slab  = blockIdx.y;          // 0..47
    const int t = threadIdx.x;
    const int wv = t >> 6, l = t & 63, q = l >> 4, ln = l & 15;
    const int n = ntile * 16 + ln;
    const int kbase = slab * 512;

    const u16*   Ab = fmn16 + (size_t)(wv * 16 + ln) * 24576 + kbase + q * 8;
    const float* Bb = fc_w + (size_t)n * 24576 + kbase + q * 8;
    const bool nok = n < 200;

    f32x4_t acc = {0.f, 0.f, 0.f, 0.f};
#pragma unroll
    for (int kk = 0; kk < 512; kk += 32) {
        Frag af, bf2;
        af.u4 = *(const uint32x4*)(Ab + kk);
        if (nok) load8_cvt(Bb + kk, bf2);
        else { bf2.u[0] = 0u; bf2.u[1] = 0u; bf2.u[2] = 0u; bf2.u[3] = 0u; }
        acc = MFMA(af.v, bf2.v, acc);
    }
#pragma unroll
    for (int r = 0; r < 4; ++r) {
        const int bb = wv * 16 + q * 4 + r;
        p_part[(size_t)(slab * 64 + bb) * 208 + ntile * 16 + ln] = acc[r];
    }
}

// ---- Pass 5: reduce 48 slabs, scale 100, + bias ----
__global__ __launch_bounds__(256) void k_fin(
    const float* __restrict__ p_part, const float* __restrict__ fc_b,
    float* __restrict__ p_out)
{
    const int tid = blockIdx.x * 256 + threadIdx.x;   // 50*256 == 12800
    const int b = tid / 200, n = tid - b * 200;
    float s = 0.f;
#pragma unroll
    for (int sl = 0; sl < 48; ++sl) s += p_part[(size_t)(sl * 64 + b) * 208 + n];
    p_out[tid] = s * 100.f + fc_b[n];
}

extern "C" void kernel_launch(void* const* d_in, const int* in_sizes, int n_in,
                              void* d_out, int out_size, void* d_ws, size_t ws_size,
                              hipStream_t stream)
{
    const float* fm    = (const float*)d_in[0];
    const float* att_w = (const float*)d_in[1];
    const float* att_b = (const float*)d_in[2];
    const float* fc_w  = (const float*)d_in[3];
    const float* fc_b  = (const float*)d_in[4];

    float* out     = (float*)d_out;
    float* p_out   = out;                         // [64][200]
    float* fm_out  = out + 12800;                 // [64][32][768]
    float* att_out = out + 12800 + 64 * 32 * 768; // [64][32][676]

    char* ws = (char*)d_ws;
    const size_t PART_B = 25165824;   // [4][64][32][768] f32
    const size_t POOL_B = 6291456;    // [64][32][768] f32
    const size_t FMN_B  = 3145728;    // [64][24576] bf16
    const bool use_part = ws_size >= PART_B + POOL_B + FMN_B + 1024;

    float* pooled; float* p_part; float* p_sums; u16* fmn16; float* part = nullptr;
    if (use_part) {
        part   = (float*)ws;
        pooled = (float*)(ws + PART_B);
        fmn16  = (u16*)(ws + PART_B + POOL_B);
        p_sums = (float*)(ws + PART_B + POOL_B + FMN_B);
        p_part = (float*)ws;                      // overlays part (dead by k_fc)
    } else {
        pooled = (float*)ws;
        fmn16  = (u16*)(ws + POOL_B);
        p_sums = (float*)(ws + POOL_B + FMN_B);
        p_part = (float*)ws;                      // overlays pooled (dead by k_fc)
        hipMemsetAsync(pooled, 0, POOL_B, stream);
    }

    static int attr_done = 0;
    if (!attr_done) {
        hipFuncSetAttribute(reinterpret_cast<const void*>(&k_fused<true>),
            hipFuncAttributeMaxDynamicSharedMemorySize, LDS_BYTES);
        hipFuncSetAttribute(reinterpret_cast<const void*>(&k_fused<false>),
            hipFuncAttributeMaxDynamicSharedMemorySize, LDS_BYTES);
        attr_done = 1;
    }

    if (use_part) {
        k_fused<true><<<dim3(4, 64), 512, LDS_BYTES, stream>>>(
            fm, att_w, att_b, att_out, part);
        k_psum<true><<<dim3(64, 4), 256, 0, stream>>>(part, pooled, p_sums);
    } else {
        k_fused<false><<<dim3(4, 64), 512, LDS_BYTES, stream>>>(
            fm, att_w, att_b, att_out, pooled);
        k_psum<false><<<dim3(64, 4), 256, 0, stream>>>(pooled, pooled, p_sums);
    }
    k_norm<<<dim3(64, 12), 256, 0, stream>>>(pooled, p_sums, fm_out, fmn16);
    k_fc  <<<dim3(13, 48), 256, 0, stream>>>(fmn16, fc_w, p_part);
    k_fin <<<dim3(50),     256, 0, stream>>>(p_part, fc_b, p_out);
}